// Round 8
// baseline (81.281 us; speedup 1.0000x reference)
//
#include <hip/hip_runtime.h>
#include <math.h>

#define BB 32
#define CC 128
#define HW 1024
#define NG 32
#define TPG 4096
#define QSZ ((size_t)BB * 4 * HW * 32)   // elems per Q/K/V bf16 buffer

typedef __attribute__((ext_vector_type(8))) short fragAB;
typedef __attribute__((ext_vector_type(4))) float fragC;

__device__ __forceinline__ ushort f2bf(float f) {
  union { float f; uint u; } v; v.f = f;
  uint r = v.u + 0x7FFFu + ((v.u >> 16) & 1u);
  return (ushort)(r >> 16);
}
// pack two f32 -> two bf16 (truncation) in one v_perm_b32
__device__ __forceinline__ uint pack2(float lo, float hi) {
  return __builtin_amdgcn_perm(__float_as_uint(hi), __float_as_uint(lo), 0x07060302u);
}

// LDS swizzles (byte offsets).
__device__ __forceinline__ int kswz(int row, int g) {   // 64B rows, g=16B granule 0..3
  return row * 64 + 16 * (g ^ ((row >> 1) & 3));
}
__device__ __forceinline__ int vswz(int row, int g) {   // 128B rows, g 0..7
  return row * 128 + 16 * (g ^ (row & 7));
}

// ---------------- GroupNorm stats (blocks 0..1023) + weight bf16 prep (blocks 1024..1279) ----
__global__ __launch_bounds__(256) void gn_stats(const float* __restrict__ x,
    float2* __restrict__ stats, const float* __restrict__ qkvw,
    const float* __restrict__ projw, ushort* __restrict__ wq16,
    ushort* __restrict__ wp16) {
  if (blockIdx.x >= 1024) {               // weight conversion side-grid
    int idx = (blockIdx.x - 1024) * 256 + threadIdx.x;   // 0..65535
    if (idx < 49152) wq16[idx] = f2bf(qkvw[idx]);
    else             wp16[idx - 49152] = f2bf(projw[idx - 49152]);
    return;
  }
  int blk = blockIdx.x;          // b*NG + g
  int b = blk >> 5, g = blk & 31;
  const float4* xp4 = (const float4*)(x + ((size_t)(b * CC + g * 4)) * HW);
  float s = 0.f, s2 = 0.f;
  #pragma unroll
  for (int i = 0; i < 4; ++i) {
    float4 v = xp4[threadIdx.x + i * 256];
    s  += v.x + v.y + v.z + v.w;
    s2 += v.x * v.x + v.y * v.y + v.z * v.z + v.w * v.w;
  }
  #pragma unroll
  for (int off = 32; off; off >>= 1) {
    s  += __shfl_down(s, off, 64);
    s2 += __shfl_down(s2, off, 64);
  }
  __shared__ float ls[4], ls2[4];
  int lane = threadIdx.x & 63, wid = threadIdx.x >> 6;
  if (lane == 0) { ls[wid] = s; ls2[wid] = s2; }
  __syncthreads();
  if (threadIdx.x == 0) {
    float a  = ls[0] + ls[1] + ls[2] + ls[3];
    float a2 = ls2[0] + ls2[1] + ls2[2] + ls2[3];
    float mu = a * (1.f / TPG);
    float var = a2 * (1.f / TPG) - mu * mu;
    stats[blk] = make_float2(mu, rsqrtf(var + 1e-5f));
  }
}

// ---------------- GN apply + transpose: x[b][c][t] -> xt16[b][t][c] bf16 ----------------
__global__ __launch_bounds__(256) void gn_apply(const float* __restrict__ x,
    const float2* __restrict__ stats, const float* __restrict__ gw,
    const float* __restrict__ gb, ushort* __restrict__ xt16) {
  __shared__ ushort Xs[64][136];
  int b = blockIdx.x >> 4, t0 = (blockIdx.x & 15) * 64;
  int tid = threadIdx.x;
  int tq = tid & 15, cg = (tid >> 4) & 3, wv = tid >> 6;

  #pragma unroll
  for (int iter = 0; iter < 8; ++iter) {
    int c = wv * 4 + cg + iter * 16;
    float2 st = stats[b * 32 + (c >> 2)];
    float wsc = gw[c] * st.y;
    float bsc = gb[c] - st.x * wsc;
    const float* xp = x + ((size_t)b * CC + c) * HW + t0;
    #pragma unroll
    for (int j = 0; j < 4; ++j) {
      int t = tq + 16 * j;
      Xs[t][c] = f2bf(xp[t] * wsc + bsc);
    }
  }
  __syncthreads();
  #pragma unroll
  for (int it = 0; it < 4; ++it) {
    int row = (tid >> 4) + it * 16;
    int c8 = tid & 15;
    uint4 v = *(uint4*)&Xs[row][c8 * 8];
    *(uint4*)&xt16[((size_t)b * HW + t0 + row) * CC + c8 * 8] = v;
  }
}

// ---------------- MFMA GEMM: D[o,t] = sum_c W[o,c] * X[t,c] ----------------
template<int PROJ>
__global__ __launch_bounds__(256) void mgemm(
    const ushort* __restrict__ W16, const ushort* __restrict__ X16,
    ushort* __restrict__ Qb, float* __restrict__ out,
    const float* __restrict__ bias, const float* __restrict__ resid) {
  __shared__ ushort Xs[64 * 128];    // 16KB, XOR-swizzled byte ^= ((row&7)<<4)
  int b = blockIdx.z, o0 = blockIdx.y * 64, t0 = blockIdx.x * 64;
  int tid = threadIdx.x;
  int lane = tid & 63, w = tid >> 6, lc = lane & 15, lg = lane >> 4;
  int wo = w >> 1, wt = w & 1;

  fragAB af[2][4];
  #pragma unroll
  for (int i = 0; i < 2; ++i)
    #pragma unroll
    for (int kc = 0; kc < 4; ++kc)
      af[i][kc] = *(const fragAB*)&W16[(size_t)(o0 + wo * 32 + i * 16 + lc) * 128 + kc * 32 + lg * 8];

  {
    const char* src = (const char*)(X16 + ((size_t)b * HW + t0) * CC);
    char* dst = (char*)Xs;
    #pragma unroll
    for (int it = 0; it < 4; ++it) {
      int flat = tid * 16 + it * 4096;
      uint4 v = *(const uint4*)(src + flat);
      *(uint4*)(dst + (flat ^ (((flat >> 8) & 7) << 4))) = v;
    }
  }
  __syncthreads();

  fragC acc[2][2];
  #pragma unroll
  for (int i = 0; i < 2; ++i)
    #pragma unroll
    for (int j = 0; j < 2; ++j)
      acc[i][j] = (fragC){0.f, 0.f, 0.f, 0.f};

  #pragma unroll
  for (int kc = 0; kc < 4; ++kc) {
    fragAB bf[2];
    #pragma unroll
    for (int j = 0; j < 2; ++j) {
      int row = wt * 32 + j * 16 + lc;
      int byt = (row * 256 + kc * 64 + lg * 16) ^ ((row & 7) << 4);
      bf[j] = *(const fragAB*)((const char*)Xs + byt);
    }
    #pragma unroll
    for (int i = 0; i < 2; ++i)
      #pragma unroll
      for (int j = 0; j < 2; ++j)
        acc[i][j] = __builtin_amdgcn_mfma_f32_16x16x32_bf16(af[i][kc], bf[j], acc[i][j], 0, 0, 0);
  }

  if constexpr (PROJ == 0) {
    #pragma unroll
    for (int i = 0; i < 2; ++i) {
      int ob = o0 + wo * 32 + i * 16;
      int blk = ob >> 5;
      int hh = blk / 3, kind = blk % 3;  // 0=q,1=k,2=v
      int cb = ob & 16;
      size_t bh = (size_t)b * 4 + hh;
      // q rows: fold logits scale 1/dh AND log2(e) so attn uses exp2 directly
      float sc = (kind == 0) ? (0.03125f * 1.44269504f) : 1.f;
      #pragma unroll
      for (int j = 0; j < 2; ++j) {
        int t = t0 + wt * 32 + j * 16 + lc;
        if (kind < 2) {
          ushort* dst = (kind == 0) ? Qb : (Qb + QSZ);
          ushort4 rv;
          rv.x = f2bf(acc[i][j][0] * sc); rv.y = f2bf(acc[i][j][1] * sc);
          rv.z = f2bf(acc[i][j][2] * sc); rv.w = f2bf(acc[i][j][3] * sc);
          *(ushort4*)&dst[(bh * HW + t) * 32 + cb + lg * 4] = rv;
        } else {
          ushort* Vb = Qb + 2 * QSZ;
          #pragma unroll
          for (int r = 0; r < 4; ++r)
            Vb[(bh * 32 + cb + lg * 4 + r) * HW + t] = f2bf(acc[i][j][r]);
        }
      }
    }
  } else {
    #pragma unroll
    for (int i = 0; i < 2; ++i)
      #pragma unroll
      for (int j = 0; j < 2; ++j) {
        int t = t0 + wt * 32 + j * 16 + lc;
        #pragma unroll
        for (int r = 0; r < 4; ++r) {
          int o = o0 + wo * 32 + i * 16 + lg * 4 + r;
          size_t idx = ((size_t)b * CC + o) * HW + t;
          out[idx] = acc[i][j][r] + bias[o] + resid[idx];
        }
      }
  }
}

// ---------------- MFMA flash attention v5: static softmax + deferred PV ----------------
// Q prescaled by (1/32)*log2e -> P = exp2(S). No running max (|S'| << 126 safe).
// Per iter: S-MFMAs (both ts) -> exp2/pack/Ps-write (both) -> Ps-read + PV (both).
__global__ __launch_bounds__(256, 4) void attn2(
    const ushort* __restrict__ Qb, const ushort* __restrict__ Kb,
    const ushort* __restrict__ Vb, ushort* __restrict__ ao16) {
  __shared__ char arena[32768];
  // [0,8K): Kl dbuf  [8K,16K): Vl dbuf  [16K,32K): Ps[w][2] (2KB each)
  // Ol overlaps Ps (used only after final barrier)

  int lin = blockIdx.x;
  int wl = (lin & 7) * 128 + (lin >> 3);   // XCD swizzle
  int tb = wl & 7;
  int bh = wl >> 3;
  int h = bh & 3, b = bh >> 2;

  int tid = threadIdx.x;
  int w = tid >> 6, lane = tid & 63, lc = lane & 15, lg = lane >> 4;

  const ushort* Qg = Qb + (size_t)bh * HW * 32;
  const ushort* Kg = Kb + (size_t)bh * HW * 32;
  const ushort* Vg = Vb + (size_t)bh * HW * 32;
  int t0 = tb * 128 + w * 32;

  fragAB q0 = *(const fragAB*)&Qg[(size_t)(t0 + lc) * 32 + lg * 8];
  fragAB q1 = *(const fragAB*)&Qg[(size_t)(t0 + 16 + lc) * 32 + lg * 8];

  fragC a00 = {0.f,0.f,0.f,0.f}, a01 = {0.f,0.f,0.f,0.f};
  fragC a10 = {0.f,0.f,0.f,0.f}, a11 = {0.f,0.f,0.f,0.f};
  float l0 = 0.f, l1 = 0.f;

  int kdst = kswz(tid >> 2, tid & 3);
  int vrow = tid >> 3, vg = tid & 7;
  int vdst = vswz(vrow, vg);
  char* KlB0 = arena;           char* KlB1 = arena + 4096;
  char* VlB0 = arena + 8192;    char* VlB1 = arena + 12288;
  char* PsB0 = arena + 16384 + w * 4096;
  char* PsB1 = PsB0 + 2048;

  uint4 kreg = *(const uint4*)&Kg[tid * 8];
  uint4 vreg = *(const uint4*)&Vg[(size_t)vrow * HW + vg * 8];
  *(uint4*)(KlB0 + kdst) = kreg;
  *(uint4*)(VlB0 + vdst) = vreg;
  __syncthreads();

  for (int i = 0; i < 16; ++i) {
    int cur = i & 1;
    char* KlC = cur ? KlB1 : KlB0;
    char* VlC = cur ? VlB1 : VlB0;
    if (i < 15) {
      int sn = (i + 1) * 64;
      kreg = *(const uint4*)&Kg[sn * 32 + tid * 8];
      vreg = *(const uint4*)&Vg[(size_t)vrow * HW + sn + vg * 8];
    }
    fragAB kf[4];
    #pragma unroll
    for (int j = 0; j < 4; ++j)
      kf[j] = *(const fragAB*)(KlC + kswz(j * 16 + lc, lg));
    fragAB vf[2][2];
    #pragma unroll
    for (int cs = 0; cs < 2; ++cs)
      #pragma unroll
      for (int ks = 0; ks < 2; ++ks)
        vf[cs][ks] = *(const fragAB*)(VlC + vswz(cs * 16 + lc, ks * 4 + lg));

    // ---- phase A: S-MFMAs for both ts halves ----
    fragC S0[4], S1[4];
    #pragma unroll
    for (int j = 0; j < 4; ++j) {
      fragC z = {0.f,0.f,0.f,0.f};
      S0[j] = __builtin_amdgcn_mfma_f32_16x16x32_bf16(kf[j], q0, z, 0, 0, 0);
    }
    #pragma unroll
    for (int j = 0; j < 4; ++j) {
      fragC z = {0.f,0.f,0.f,0.f};
      S1[j] = __builtin_amdgcn_mfma_f32_16x16x32_bf16(kf[j], q1, z, 0, 0, 0);
    }

    // ---- phase B: exp2 + pack + Ps writes (both halves) ----
    {
      float rs = 0.f;
      #pragma unroll
      for (int j = 0; j < 4; ++j) {
        float p0 = exp2f(S0[j][0]), p1 = exp2f(S0[j][1]);
        float p2 = exp2f(S0[j][2]), p3 = exp2f(S0[j][3]);
        rs += (p0 + p1) + (p2 + p3);
        uint2 wv2;
        wv2.x = pack2(p0, p1);
        wv2.y = pack2(p2, p3);
        int g = j * 2 + (lg >> 1);
        *(uint2*)(PsB0 + lc * 128 + 16 * (g ^ (lc & 7)) + (lg & 1) * 8) = wv2;
      }
      l0 += rs;
    }
    {
      float rs = 0.f;
      #pragma unroll
      for (int j = 0; j < 4; ++j) {
        float p0 = exp2f(S1[j][0]), p1 = exp2f(S1[j][1]);
        float p2 = exp2f(S1[j][2]), p3 = exp2f(S1[j][3]);
        rs += (p0 + p1) + (p2 + p3);
        uint2 wv2;
        wv2.x = pack2(p0, p1);
        wv2.y = pack2(p2, p3);
        int g = j * 2 + (lg >> 1);
        *(uint2*)(PsB1 + lc * 128 + 16 * (g ^ (lc & 7)) + (lg & 1) * 8) = wv2;
      }
      l1 += rs;
    }

    // ---- phase C: Ps reads + PV MFMAs ----
    fragAB bp00 = *(const fragAB*)(PsB0 + vswz(lc, lg));
    fragAB bp01 = *(const fragAB*)(PsB0 + vswz(lc, 4 + lg));
    fragAB bp10 = *(const fragAB*)(PsB1 + vswz(lc, lg));
    fragAB bp11 = *(const fragAB*)(PsB1 + vswz(lc, 4 + lg));
    __builtin_amdgcn_s_setprio(1);
    a00 = __builtin_amdgcn_mfma_f32_16x16x32_bf16(vf[0][0], bp00, a00, 0, 0, 0);
    a00 = __builtin_amdgcn_mfma_f32_16x16x32_bf16(vf[0][1], bp01, a00, 0, 0, 0);
    a10 = __builtin_amdgcn_mfma_f32_16x16x32_bf16(vf[1][0], bp00, a10, 0, 0, 0);
    a10 = __builtin_amdgcn_mfma_f32_16x16x32_bf16(vf[1][1], bp01, a10, 0, 0, 0);
    a01 = __builtin_amdgcn_mfma_f32_16x16x32_bf16(vf[0][0], bp10, a01, 0, 0, 0);
    a01 = __builtin_amdgcn_mfma_f32_16x16x32_bf16(vf[0][1], bp11, a01, 0, 0, 0);
    a11 = __builtin_amdgcn_mfma_f32_16x16x32_bf16(vf[1][0], bp10, a11, 0, 0, 0);
    a11 = __builtin_amdgcn_mfma_f32_16x16x32_bf16(vf[1][1], bp11, a11, 0, 0, 0);
    __builtin_amdgcn_s_setprio(0);

    if (i < 15) {
      char* KlN = cur ? KlB0 : KlB1;
      char* VlN = cur ? VlB0 : VlB1;
      *(uint4*)(KlN + kdst) = kreg;
      *(uint4*)(VlN + vdst) = vreg;
    }
    __syncthreads();
  }

  // single cross-lane l reduce (each lane summed a disjoint s-slice)
  l0 += __shfl_xor(l0, 16); l0 += __shfl_xor(l0, 32);
  l1 += __shfl_xor(l1, 16); l1 += __shfl_xor(l1, 32);
  float il0 = 1.f / l0, il1 = 1.f / l1;

  // O -> Ol[t][c] (80B rows; conflict-free) -> coalesced global
  ushort* Ol = (ushort*)(arena + 16384);   // overlaps Ps, safe after final barrier
  int tl = w * 32 + lc;
  uint2 u;
  u.x = pack2(a00[0] * il0, a00[1] * il0); u.y = pack2(a00[2] * il0, a00[3] * il0);
  *(uint2*)&Ol[tl * 40 + lg * 4] = u;
  u.x = pack2(a10[0] * il0, a10[1] * il0); u.y = pack2(a10[2] * il0, a10[3] * il0);
  *(uint2*)&Ol[tl * 40 + 16 + lg * 4] = u;
  u.x = pack2(a01[0] * il1, a01[1] * il1); u.y = pack2(a01[2] * il1, a01[3] * il1);
  *(uint2*)&Ol[(tl + 16) * 40 + lg * 4] = u;
  u.x = pack2(a11[0] * il1, a11[1] * il1); u.y = pack2(a11[2] * il1, a11[3] * il1);
  *(uint2*)&Ol[(tl + 16) * 40 + 16 + lg * 4] = u;
  __syncthreads();

  int row = tid >> 1, half = tid & 1;
  uint4 v0 = *(uint4*)&Ol[row * 40 + half * 16];
  uint4 v1 = *(uint4*)&Ol[row * 40 + half * 16 + 8];
  ushort* dst = &ao16[((size_t)b * HW + tb * 128 + row) * CC + h * 32 + half * 16];
  *(uint4*)dst = v0;
  *(uint4*)(dst + 8) = v1;
}

extern "C" void kernel_launch(void* const* d_in, const int* in_sizes, int n_in,
                              void* d_out, int out_size, void* d_ws, size_t ws_size,
                              hipStream_t stream) {
  (void)in_sizes; (void)n_in; (void)out_size; (void)ws_size;
  const float* x     = (const float*)d_in[0];
  const float* gw    = (const float*)d_in[1];
  const float* gb    = (const float*)d_in[2];
  const float* qkvw  = (const float*)d_in[3];
  const float* projw = (const float*)d_in[4];
  const float* projb = (const float*)d_in[5];
  float* out = (float*)d_out;

  char* wsb = (char*)d_ws;
  ushort* xt16 = (ushort*)wsb;                              // 8 MB (GN out, then attn out)
  ushort* Qb   = (ushort*)(wsb + ((size_t)8 << 20));        // 8 MB
  ushort* Kb   = Qb + QSZ;                                  // 8 MB
  ushort* Vb   = Qb + 2 * QSZ;                              // 8 MB
  ushort* wq16 = (ushort*)(wsb + ((size_t)32 << 20));       // 96 KB
  ushort* wp16 = (ushort*)(wsb + ((size_t)32 << 20) + (128 << 10)); // 32 KB
  float2* stats = (float2*)(wsb + ((size_t)32 << 20) + (256 << 10)); // 8 KB

  gn_stats<<<dim3(BB * NG + 256), 256, 0, stream>>>(x, stats, qkvw, projw, wq16, wp16);
  gn_apply<<<dim3(BB * 16), 256, 0, stream>>>(x, stats, gw, gb, xt16);
  mgemm<0><<<dim3(16, 6, BB), 256, 0, stream>>>(wq16, xt16, Qb, nullptr, nullptr, nullptr);
  attn2<<<dim3(1024), 256, 0, stream>>>(Qb, Kb, Vb, xt16);
  mgemm<1><<<dim3(16, 2, BB), 256, 0, stream>>>(wp16, xt16, nullptr, out, projb, x);
}